// Round 12
// baseline (372.099 us; speedup 1.0000x reference)
//
#include <hip/hip_runtime.h>
#include <math.h>

#define N_NODES 20000
#define E_ORIG  320000
#define E_TOT   340000
#define NUM_GRAPHS 64
#define NCHUNK 10           // src chunks of 2048 rows -> (dst,chunk) binned CSR
#define NBINS (N_NODES * NCHUNK)
#define SCAN_BLOCKS 196     // 196 * 1024 = 200704 >= NBINS
#define GBLOCKS 1536        // 6 blocks/CU co-resident -> 6144 waves
#define GWAVES  (GBLOCKS * 4)
#define NODES_PER_WAVE 4    // 4 * 6144 = 24576 >= N_NODES

typedef __attribute__((ext_vector_type(8))) short bf16x8;
typedef __attribute__((ext_vector_type(4))) float f32x4;

// fp32 -> bf16 RNE
__device__ __forceinline__ ushort f2bf(float x) {
  unsigned u = __float_as_uint(x);
  return (ushort)((u + 0x7fffu + ((u >> 16) & 1u)) >> 16);
}
// 4 consecutive bf16 -> float4 (8B load)
__device__ __forceinline__ float4 ld_bf16x4(const ushort* p) {
  ushort4 u = *(const ushort4*)p;
  float4 f;
  f.x = __uint_as_float((unsigned)u.x << 16);
  f.y = __uint_as_float((unsigned)u.y << 16);
  f.z = __uint_as_float((unsigned)u.z << 16);
  f.w = __uint_as_float((unsigned)u.w << 16);
  return f;
}
// async global->LDS, 16B per lane; lds dest is wave-uniform base + lane*16
__device__ __forceinline__ void gl_lds16(const void* g, void* l) {
  __builtin_amdgcn_global_load_lds(
      (const __attribute__((address_space(1))) unsigned*)(uintptr_t)g,
      (__attribute__((address_space(3))) unsigned*)(uintptr_t)l, 16, 0, 0);
}

// ============ merged prep: cast x, pack weights, zero (dst,chunk) bins ======
__global__ __launch_bounds__(256) void prep(
    const float* __restrict__ x,
    const float* __restrict__ Wl0, const float* __restrict__ Wr0,
    const float* __restrict__ Wl1, const float* __restrict__ Wr1,
    const float* __restrict__ Wl2, const float* __restrict__ Wr2,
    ushort* __restrict__ x16, ushort* __restrict__ Bt0,
    ushort* __restrict__ Bt1, ushort* __restrict__ Bt2, int* __restrict__ deg)
{
  const int Z0 = 640000;           // x cast, float4 granules (20000*128/4)
  const int Z1 = Z0 + 65536;       // Bt0: 512(n) x 128(k)
  const int Z2 = Z1 + 131072;      // Bt1: 512 x 256
  const int Z3 = Z2 + 32768;       // Bt2: 128 x 256
  const int Z4 = Z3 + NBINS / 4;   // deg zero, int4 granules (200000 ints)
  int t = blockIdx.x * 256 + threadIdx.x;
  if (t < Z0) {
    int i = t << 2;
    float4 v = *(const float4*)&x[i];
    ushort4 o; o.x = f2bf(v.x); o.y = f2bf(v.y); o.z = f2bf(v.z); o.w = f2bf(v.w);
    *(ushort4*)&x16[i] = o;
  } else if (t < Z1) {
    int idx = t - Z0; int n = idx >> 7, k = idx & 127;
    float v = (n < 256) ? Wl0[k * 256 + n] : Wr0[k * 256 + (n - 256)];
    Bt0[idx] = f2bf(v);
  } else if (t < Z2) {
    int idx = t - Z1; int n = idx >> 8, k = idx & 255;
    float v = (n < 256) ? Wl1[k * 256 + n] : Wr1[k * 256 + (n - 256)];
    Bt1[idx] = f2bf(v);
  } else if (t < Z3) {
    int idx = t - Z2; int n = idx >> 8, k = idx & 255;
    float v = (n < 64) ? Wl2[k * 64 + n] : Wr2[k * 64 + (n - 64)];
    Bt2[idx] = f2bf(v);
  } else if (t < Z4) {
    int4 z = {0, 0, 0, 0};
    *(int4*)&deg[(t - Z3) << 2] = z;
  }
}

// ============ CSR build, binned by (dst, src-chunk of 2048) ============

__global__ __launch_bounds__(256) void deg_count(
    const int* __restrict__ esrc, const int* __restrict__ edst,
    int* __restrict__ deg)
{
  int e = blockIdx.x * 256 + threadIdx.x;
  if (e >= E_TOT) return;
  int src, dst;
  if (e < E_ORIG) { src = esrc[e]; dst = edst[e]; }
  else            { src = dst = e - E_ORIG; }
  atomicAdd(&deg[dst * NCHUNK + (src >> 11)], 1);
}

// phase 1: per-block (1024 ints) reduction -> bsum[SCAN_BLOCKS]
__global__ __launch_bounds__(256) void scan1(
    const int* __restrict__ deg, int* __restrict__ bsum)
{
  __shared__ int red[256];
  const int t = threadIdx.x;
  int base = (blockIdx.x << 10) + (t << 2);
  int s = 0;
  if (base + 4 <= NBINS) {
    int4 v = *(const int4*)&deg[base];
    s = v.x + v.y + v.z + v.w;
  }
  red[t] = s;
  __syncthreads();
  #pragma unroll
  for (int off = 128; off > 0; off >>= 1) {
    if (t < off) red[t] += red[t + off];
    __syncthreads();
  }
  if (t == 0) bsum[blockIdx.x] = red[0];
}

// phase 2 (merged): each block scans the 196 partials in LDS, then local scan
__global__ __launch_bounds__(256) void scan3(
    const int* __restrict__ deg, const int* __restrict__ bsum,
    int* __restrict__ rowptr, int* __restrict__ cursor)
{
  __shared__ int sc[256];
  __shared__ int bs[256];
  const int t = threadIdx.x;
  bs[t] = (t < SCAN_BLOCKS) ? bsum[t] : 0;
  __syncthreads();
  #pragma unroll
  for (int off = 1; off < 256; off <<= 1) {
    int v = (t >= off) ? bs[t - off] : 0;
    __syncthreads();
    bs[t] += v;
    __syncthreads();
  }
  const int myoff = (blockIdx.x == 0) ? 0 : bs[blockIdx.x - 1];

  int base = (blockIdx.x << 10) + (t << 2);
  int4 v = {0, 0, 0, 0};
  if (base + 4 <= NBINS) v = *(const int4*)&deg[base];
  int s = v.x + v.y + v.z + v.w;
  sc[t] = s;
  __syncthreads();
  #pragma unroll
  for (int off = 1; off < 256; off <<= 1) {
    int u = (t >= off) ? sc[t - off] : 0;
    __syncthreads();
    sc[t] += u;
    __syncthreads();
  }
  if (base + 4 <= NBINS) {
    int p = myoff + ((t == 0) ? 0 : sc[t - 1]);
    int4 r;
    r.x = p; r.y = p + v.x; r.z = r.y + v.y; r.w = r.z + v.z;
    *(int4*)&rowptr[base] = r;
    *(int4*)&cursor[base] = r;
  }
  if (blockIdx.x == SCAN_BLOCKS - 1 && t == 255) rowptr[NBINS] = bs[255];
}

__global__ __launch_bounds__(256) void csr_fill(
    const int* __restrict__ esrc, const int* __restrict__ edst,
    int* __restrict__ cursor, int* __restrict__ csr_src)
{
  int e = blockIdx.x * 256 + threadIdx.x;
  if (e >= E_TOT) return;
  int src, dst;
  if (e < E_ORIG) { src = esrc[e]; dst = edst[e]; }
  else            { src = dst = e - E_ORIG; }
  int pos = atomicAdd(&cursor[dst * NCHUNK + (src >> 11)], 1);
  csr_src[pos] = src;
}

// ============ bf16 MFMA GEMM: [Cl|Cr][M,N] = A[M,K] @ Bt[N,K]^T ============
__global__ __launch_bounds__(256) void mfma_gemm_bf16(
    const ushort* __restrict__ A, const ushort* __restrict__ Bt,
    ushort* __restrict__ Cl, ushort* __restrict__ Cr, int M, int K, int N)
{
  __shared__ char smem[36864];
  ushort* As = (ushort*)smem;           // [128][64]
  ushort* Bs = As + 8192;               // [128][64]

  const int mtiles = (M + 127) >> 7;
  const int bid = blockIdx.x;
  const int xcd = bid & 7;
  const int i = bid >> 3;
  const int n0 = (i / 20) << 7;
  const int m = xcd + ((i % 20) << 3);
  if (m >= mtiles) return;
  const int m0 = m << 7;

  const int tid = threadIdx.x;
  const int lane = tid & 63;
  const int w = tid >> 6;
  const int wm = (w >> 1) << 6;
  const int wn = (w & 1) << 6;
  const int quad = lane >> 4;
  const int l15 = lane & 15;

  f32x4 acc[4][4] = {};

  for (int k0 = 0; k0 < K; k0 += 64) {
    #pragma unroll
    for (int r = 0; r < 4; r++) {
      int c = (r << 8) + tid;
      int row = c >> 3;
      int col = (c & 7) << 3;
      int ga = m0 + row; if (ga >= M) ga = M - 1;
      gl_lds16(A  + (size_t)ga * K + k0 + col, (char*)As + c * 16);
      gl_lds16(Bt + (size_t)(n0 + row) * K + k0 + col, (char*)Bs + c * 16);
    }
    __syncthreads();
    #pragma unroll
    for (int ks = 0; ks < 2; ks++) {
      bf16x8 af[4], bfr[4];
      #pragma unroll
      for (int ii = 0; ii < 4; ii++)
        af[ii]  = *(const bf16x8*)&As[(wm + (ii << 4) + l15) * 64 + (ks << 5) + (quad << 3)];
      #pragma unroll
      for (int j = 0; j < 4; j++)
        bfr[j] = *(const bf16x8*)&Bs[(wn + (j << 4) + l15) * 64 + (ks << 5) + (quad << 3)];
      #pragma unroll
      for (int ii = 0; ii < 4; ii++)
        #pragma unroll
        for (int j = 0; j < 4; j++)
          acc[ii][j] = __builtin_amdgcn_mfma_f32_16x16x32_bf16(
              af[ii], bfr[j], acc[ii][j], 0, 0, 0);
    }
    __syncthreads();
  }

  // route this wave's 64-col stripe to Cl or Cr (wave-uniform)
  const int halfN = N >> 1;
  const int gc0 = n0 + wn;
  ushort* Cd = (gc0 < halfN) ? Cl : Cr;
  const int cb = (gc0 < halfN) ? gc0 : gc0 - halfN;

  ushort* Cs = (ushort*)smem + w * 4608;
  #pragma unroll
  for (int ii = 0; ii < 4; ii++)
    #pragma unroll
    for (int j = 0; j < 4; j++)
      #pragma unroll
      for (int r = 0; r < 4; r++)
        Cs[((ii << 4) + (quad << 2) + r) * 72 + (j << 4) + l15] = f2bf(acc[ii][j][r]);
  #pragma unroll
  for (int it = 0; it < 8; it++) {
    int row = (it << 3) + (lane >> 3);
    int cc = lane & 7;
    bf16x8 v = *(const bf16x8*)&Cs[row * 72 + (cc << 3)];
    int grow = m0 + wm + row;
    if (grow < M)
      *(bf16x8*)&Cd[(size_t)grow * halfN + cb + (cc << 3)] = v;
  }
}

// ============ GATv2 edge phase helpers ============
__device__ __forceinline__ void h4_term(
    float4 xlv, const float4& xrv, const float4& attv, float& v)
{
  float4 a;
  a.x = xlv.x + xrv.x; a.y = xlv.y + xrv.y;
  a.z = xlv.z + xrv.z; a.w = xlv.w + xrv.w;
  a.x = fmaxf(a.x, 0.2f * a.x); a.y = fmaxf(a.y, 0.2f * a.y);
  a.z = fmaxf(a.z, 0.2f * a.z); a.w = fmaxf(a.w, 0.2f * a.w);
  v = a.x * attv.x + a.y * attv.y + a.z * attv.z + a.w * attv.w;
}

__device__ __forceinline__ void h4_edge(
    const float4& xv, const float4& xrv, const float4& attv,
    float4& acc, float& lsum)
{
  float v;
  h4_term(xv, xrv, attv, v);
  v += __shfl_xor(v, 1);
  v += __shfl_xor(v, 2);
  v += __shfl_xor(v, 4);
  v += __shfl_xor(v, 8);
  float w = __expf(v);            // no-max softmax: logits O(1), safe
  lsum += w;
  acc.x += w * xv.x; acc.y += w * xv.y;
  acc.z += w * xv.z; acc.w += w * xv.w;
}

// ============ H=4 gather: persistent lockstep chunk-phased, high occupancy ==
// 1536 blocks x 6/CU co-resident (launch_bounds(256,6)) = 6144 waves, all
// resident simultaneously -> no churn; 24 waves/CU hides L2 latency (R11's
// regression was 16 waves/CU). Chunk-major loop: concurrent reads focus on
// one ~1MB xl window per phase (R11 measured FETCH 152->42 MB).
// Per-node edge order identical to binned-CSR order (bit-compatible).
__global__ __launch_bounds__(256, 6) void gat_gather_h4(
    const ushort* __restrict__ xl16, const ushort* __restrict__ xr16,
    const float* __restrict__ att, const float* __restrict__ bias,
    const int* __restrict__ rowptr, const int* __restrict__ csr_src,
    ushort* __restrict__ hout)
{
  const int wv = blockIdx.x * 4 + (threadIdx.x >> 6);   // 0..6143
  const int lane = threadIdx.x & 63;
  const int c4 = lane << 2;
  const float4 attv = *(const float4*)&att[c4];

  float4 xrv[NODES_PER_WAVE];
  float4 acc[NODES_PER_WAVE];
  float lsum[NODES_PER_WAVE];
  #pragma unroll
  for (int i = 0; i < NODES_PER_WAVE; i++) {
    int n = wv + i * GWAVES;
    acc[i] = make_float4(0.f, 0.f, 0.f, 0.f);
    lsum[i] = 0.f;
    if (n < N_NODES) xrv[i] = ld_bf16x4(xr16 + (size_t)n * 256 + c4);
  }

  for (int c = 0; c < NCHUNK; c++) {
    #pragma unroll
    for (int i = 0; i < NODES_PER_WAVE; i++) {
      const int n = wv + i * GWAVES;
      if (n >= N_NODES) continue;            // wave-uniform
      const int b = n * NCHUNK + c;
      int p = rowptr[b];
      const int e = rowptr[b + 1];
      for (; p + 3 < e; p += 4) {
        int s0 = csr_src[p],     s1 = csr_src[p + 1];
        int s2 = csr_src[p + 2], s3 = csr_src[p + 3];
        float4 x0 = ld_bf16x4(xl16 + (size_t)s0 * 256 + c4);
        float4 x1 = ld_bf16x4(xl16 + (size_t)s1 * 256 + c4);
        float4 x2 = ld_bf16x4(xl16 + (size_t)s2 * 256 + c4);
        float4 x3 = ld_bf16x4(xl16 + (size_t)s3 * 256 + c4);
        h4_edge(x0, xrv[i], attv, acc[i], lsum[i]);
        h4_edge(x1, xrv[i], attv, acc[i], lsum[i]);
        h4_edge(x2, xrv[i], attv, acc[i], lsum[i]);
        h4_edge(x3, xrv[i], attv, acc[i], lsum[i]);
      }
      for (; p < e; p++) {
        int s0 = csr_src[p];
        float4 x0 = ld_bf16x4(xl16 + (size_t)s0 * 256 + c4);
        h4_edge(x0, xrv[i], attv, acc[i], lsum[i]);
      }
    }
  }

  const float4 bv = *(const float4*)&bias[c4];
  #pragma unroll
  for (int i = 0; i < NODES_PER_WAVE; i++) {
    int n = wv + i * GWAVES;
    if (n >= N_NODES) continue;
    float inv = 1.f / lsum[i];
    ushort4 o;
    o.x = f2bf(acc[i].x * inv + bv.x); o.y = f2bf(acc[i].y * inv + bv.y);
    o.z = f2bf(acc[i].z * inv + bv.z); o.w = f2bf(acc[i].w * inv + bv.w);
    *(ushort4*)&hout[(size_t)n * 256 + c4] = o;
  }
}

// ============ layer 2 (H=1): 16-lane groups (2.5MB table, L2-resident) =====
__global__ __launch_bounds__(256) void gat_gather_h1(
    const ushort* __restrict__ xl2, const ushort* __restrict__ xr2,
    const float* __restrict__ att, const float* __restrict__ bias,
    const int* __restrict__ rowptr, const int* __restrict__ csr_src,
    float* __restrict__ h3)
{
  const int n = blockIdx.x * 4 + (threadIdx.x >> 6);
  const int lane = threadIdx.x & 63;
  const int g = lane >> 4, c4 = (lane & 15) << 2;
  const float4 xrv  = ld_bf16x4(xr2 + (size_t)n * 64 + c4);
  const float4 attv = *(const float4*)&att[c4];
  const int beg = rowptr[n * NCHUNK], end = rowptr[n * NCHUNK + NCHUNK];
  float4 acc = make_float4(0.f, 0.f, 0.f, 0.f);
  float lsum = 0.f;
  int p = beg + g;
  for (; p + 4 < end; p += 8) {        // 2 strided edges in flight
    int s0 = csr_src[p], s1 = csr_src[p + 4];
    float4 x0 = ld_bf16x4(xl2 + (size_t)s0 * 64 + c4);
    float4 x1 = ld_bf16x4(xl2 + (size_t)s1 * 64 + c4);
    h4_edge(x0, xrv, attv, acc, lsum);
    h4_edge(x1, xrv, attv, acc, lsum);
  }
  if (p < end) {
    int s0 = csr_src[p];
    float4 x0 = ld_bf16x4(xl2 + (size_t)s0 * 64 + c4);
    h4_edge(x0, xrv, attv, acc, lsum);
  }
  #pragma unroll
  for (int off = 16; off <= 32; off <<= 1) {
    lsum  += __shfl_xor(lsum, off);
    acc.x += __shfl_xor(acc.x, off); acc.y += __shfl_xor(acc.y, off);
    acc.z += __shfl_xor(acc.z, off); acc.w += __shfl_xor(acc.w, off);
  }
  if (g == 0) {
    const float4 bv = *(const float4*)&bias[c4];
    float inv = 1.f / lsum;
    float4 o;
    o.x = acc.x * inv + bv.x; o.y = acc.y * inv + bv.y;
    o.z = acc.z * inv + bv.z; o.w = acc.w * inv + bv.w;
    *(float4*)&h3[(size_t)n * 64 + c4] = o;
  }
}

// ============ fused segmented pool (batch sorted) + BN + fc ============
__global__ __launch_bounds__(256) void pool_bn_fc(
    const float* __restrict__ h3, const int* __restrict__ batch,
    const float* __restrict__ gamma, const float* __restrict__ beta,
    const float* __restrict__ mean, const float* __restrict__ var,
    const float* __restrict__ fcw, const float* __restrict__ fcb,
    float* __restrict__ out)
{
  __shared__ float red[256];
  __shared__ float s[64];
  const int g = blockIdx.x;
  const int t = threadIdx.x;
  const int c = t & 63, r = t >> 6;
  int lo = 0, hi = N_NODES;
  while (lo < hi) { int mid = (lo + hi) >> 1; if (batch[mid] < g) lo = mid + 1; else hi = mid; }
  int s0 = lo;
  hi = N_NODES;
  while (lo < hi) { int mid = (lo + hi) >> 1; if (batch[mid] < g + 1) lo = mid + 1; else hi = mid; }
  int e0 = lo;
  float a = 0.f;
  for (int n = s0 + r; n < e0; n += 4) a += h3[(size_t)n * 64 + c];
  red[t] = a;
  __syncthreads();
  if (r == 0) {
    float p = red[c] + red[c + 64] + red[c + 128] + red[c + 192];
    s[c] = (p - mean[c]) * rsqrtf(var[c] + 1e-5f) * gamma[c] + beta[c];
  }
  __syncthreads();
  if (t < 32) {
    float acc = fcb[t];
    #pragma unroll
    for (int k = 0; k < 64; k++) acc += s[k] * fcw[k * 32 + t];
    out[g * 32 + t] = acc;
  }
}

extern "C" void kernel_launch(void* const* d_in, const int* in_sizes, int n_in,
                              void* d_out, int out_size, void* d_ws, size_t ws_size,
                              hipStream_t stream) {
  const float* x    = (const float*)d_in[0];
  const int*   ei   = (const int*)d_in[1];
  const int*   batch= (const int*)d_in[2];
  const float* Wl0  = (const float*)d_in[3];
  const float* Wr0  = (const float*)d_in[4];
  const float* att0 = (const float*)d_in[5];
  const float* b0   = (const float*)d_in[6];
  const float* Wl1  = (const float*)d_in[7];
  const float* Wr1  = (const float*)d_in[8];
  const float* att1 = (const float*)d_in[9];
  const float* b1   = (const float*)d_in[10];
  const float* Wl2  = (const float*)d_in[11];
  const float* Wr2  = (const float*)d_in[12];
  const float* att2 = (const float*)d_in[13];
  const float* b2   = (const float*)d_in[14];
  const float* bng  = (const float*)d_in[15];
  const float* bnb  = (const float*)d_in[16];
  const float* bnm  = (const float*)d_in[17];
  const float* bnv  = (const float*)d_in[18];
  const float* fcw  = (const float*)d_in[19];
  const float* fcb  = (const float*)d_in[20];
  float* out = (float*)d_out;

  const int* esrc = ei;
  const int* edst = ei + E_ORIG;

  // ---- workspace layout ----
  char* w = (char*)d_ws;
  ushort* x16  = (ushort*)w;                 w += (size_t)N_NODES * 128 * 2;
  ushort* h16  = (ushort*)w;                 w += (size_t)N_NODES * 256 * 2;
  ushort* xl16 = (ushort*)w;                 w += (size_t)N_NODES * 256 * 2;
  ushort* xr16 = (ushort*)w;                 w += (size_t)N_NODES * 256 * 2;
  ushort* xl2  = (ushort*)w;                 w += (size_t)N_NODES * 64 * 2;
  ushort* xr2  = (ushort*)w;                 w += (size_t)N_NODES * 64 * 2;
  float*  h3   = (float*)w;                  w += (size_t)N_NODES * 64 * 4;
  ushort* Bt0  = (ushort*)w;                 w += (size_t)512 * 128 * 2;
  ushort* Bt1  = (ushort*)w;                 w += (size_t)512 * 256 * 2;
  ushort* Bt2  = (ushort*)w;                 w += (size_t)128 * 256 * 2;
  int* deg     = (int*)w;                    w += NBINS * 4;
  int* rowptr  = (int*)w;                    w += (NBINS + 1) * 4;
  int* cursor  = (int*)w;                    w += NBINS * 4;
  int* bsum    = (int*)w;                    w += 256 * 4;
  int* csr_src = (int*)w;

  dim3 blk(256);
  const int eblk = (E_TOT + 255) / 256;

  // ---- prep: cast + pack all weights + zero bins (one launch) ----
  prep<<<dim3(3592), blk, 0, stream>>>(
      x, Wl0, Wr0, Wl1, Wr1, Wl2, Wr2, x16, Bt0, Bt1, Bt2, deg);

  // ---- CSR build, (dst, src-chunk) binned; 2-kernel parallel scan ----
  deg_count<<<dim3(eblk), blk, 0, stream>>>(esrc, edst, deg);
  scan1<<<dim3(SCAN_BLOCKS), blk, 0, stream>>>(deg, bsum);
  scan3<<<dim3(SCAN_BLOCKS), blk, 0, stream>>>(deg, bsum, rowptr, cursor);
  csr_fill<<<dim3(eblk), blk, 0, stream>>>(esrc, edst, cursor, csr_src);

  // ---- layer 0 ----
  mfma_gemm_bf16<<<dim3(160 * 4), blk, 0, stream>>>(
      x16, Bt0, xl16, xr16, N_NODES, 128, 512);
  gat_gather_h4<<<dim3(GBLOCKS), blk, 0, stream>>>(
      xl16, xr16, att0, b0, rowptr, csr_src, h16);

  // ---- layer 1 ----
  mfma_gemm_bf16<<<dim3(160 * 4), blk, 0, stream>>>(
      h16, Bt1, xl16, xr16, N_NODES, 256, 512);
  gat_gather_h4<<<dim3(GBLOCKS), blk, 0, stream>>>(
      xl16, xr16, att1, b1, rowptr, csr_src, h16);

  // ---- layer 2 ----
  mfma_gemm_bf16<<<dim3(160 * 1), blk, 0, stream>>>(
      h16, Bt2, xl2, xr2, N_NODES, 256, 128);
  gat_gather_h1<<<dim3(N_NODES / 4), blk, 0, stream>>>(
      xl2, xr2, att2, b2, rowptr, csr_src, h3);

  // ---- pool + BN + fc ----
  pool_bn_fc<<<dim3(NUM_GRAPHS), blk, 0, stream>>>(
      h3, batch, bng, bnb, bnm, bnv, fcw, fcb, out);
}

// Round 13
// 285.766 us; speedup vs baseline: 1.3021x; 1.3021x over previous
//
#include <hip/hip_runtime.h>
#include <math.h>

#define N_NODES 20000
#define E_ORIG  320000
#define E_TOT   340000
#define NUM_GRAPHS 64
#define NCHUNK 5            // src chunks of 4096 rows -> (dst,chunk) binned CSR
#define NBINS (N_NODES * NCHUNK)
#define SCAN_BLOCKS 98      // 98 * 1024 = 100352 >= NBINS

typedef __attribute__((ext_vector_type(8))) short bf16x8;
typedef __attribute__((ext_vector_type(4))) float f32x4;

// fp32 -> bf16 RNE
__device__ __forceinline__ ushort f2bf(float x) {
  unsigned u = __float_as_uint(x);
  return (ushort)((u + 0x7fffu + ((u >> 16) & 1u)) >> 16);
}
// 4 consecutive bf16 -> float4 (8B load)
__device__ __forceinline__ float4 ld_bf16x4(const ushort* p) {
  ushort4 u = *(const ushort4*)p;
  float4 f;
  f.x = __uint_as_float((unsigned)u.x << 16);
  f.y = __uint_as_float((unsigned)u.y << 16);
  f.z = __uint_as_float((unsigned)u.z << 16);
  f.w = __uint_as_float((unsigned)u.w << 16);
  return f;
}
// async global->LDS, 16B per lane; lds dest is wave-uniform base + lane*16
__device__ __forceinline__ void gl_lds16(const void* g, void* l) {
  __builtin_amdgcn_global_load_lds(
      (const __attribute__((address_space(1))) unsigned*)(uintptr_t)g,
      (__attribute__((address_space(3))) unsigned*)(uintptr_t)l, 16, 0, 0);
}

// ============ merged prep: cast x, pack weights, zero (dst,chunk) bins ======
__global__ __launch_bounds__(256) void prep(
    const float* __restrict__ x,
    const float* __restrict__ Wl0, const float* __restrict__ Wr0,
    const float* __restrict__ Wl1, const float* __restrict__ Wr1,
    const float* __restrict__ Wl2, const float* __restrict__ Wr2,
    ushort* __restrict__ x16, ushort* __restrict__ Bt0,
    ushort* __restrict__ Bt1, ushort* __restrict__ Bt2, int* __restrict__ deg)
{
  const int Z0 = 640000;           // x cast, float4 granules (20000*128/4)
  const int Z1 = Z0 + 65536;       // Bt0: 512(n) x 128(k)
  const int Z2 = Z1 + 131072;      // Bt1: 512 x 256
  const int Z3 = Z2 + 32768;       // Bt2: 128 x 256
  const int Z4 = Z3 + NBINS / 4;   // deg zero, int4 granules (100000 ints)
  int t = blockIdx.x * 256 + threadIdx.x;
  if (t < Z0) {
    int i = t << 2;
    float4 v = *(const float4*)&x[i];
    ushort4 o; o.x = f2bf(v.x); o.y = f2bf(v.y); o.z = f2bf(v.z); o.w = f2bf(v.w);
    *(ushort4*)&x16[i] = o;
  } else if (t < Z1) {
    int idx = t - Z0; int n = idx >> 7, k = idx & 127;
    float v = (n < 256) ? Wl0[k * 256 + n] : Wr0[k * 256 + (n - 256)];
    Bt0[idx] = f2bf(v);
  } else if (t < Z2) {
    int idx = t - Z1; int n = idx >> 8, k = idx & 255;
    float v = (n < 256) ? Wl1[k * 256 + n] : Wr1[k * 256 + (n - 256)];
    Bt1[idx] = f2bf(v);
  } else if (t < Z3) {
    int idx = t - Z2; int n = idx >> 8, k = idx & 255;
    float v = (n < 64) ? Wl2[k * 64 + n] : Wr2[k * 64 + (n - 64)];
    Bt2[idx] = f2bf(v);
  } else if (t < Z4) {
    int4 z = {0, 0, 0, 0};
    *(int4*)&deg[(t - Z3) << 2] = z;
  }
}

// ============ CSR build, binned by (dst, src-chunk) ============

__global__ __launch_bounds__(256) void deg_count(
    const int* __restrict__ esrc, const int* __restrict__ edst,
    int* __restrict__ deg)
{
  int e = blockIdx.x * 256 + threadIdx.x;
  if (e >= E_TOT) return;
  int src, dst;
  if (e < E_ORIG) { src = esrc[e]; dst = edst[e]; }
  else            { src = dst = e - E_ORIG; }
  atomicAdd(&deg[dst * NCHUNK + (src >> 12)], 1);
}

// phase 1: per-block (1024 ints) reduction -> bsum[SCAN_BLOCKS]
__global__ __launch_bounds__(256) void scan1(
    const int* __restrict__ deg, int* __restrict__ bsum)
{
  __shared__ int red[256];
  const int t = threadIdx.x;
  int base = (blockIdx.x << 10) + (t << 2);
  int s = 0;
  if (base + 4 <= NBINS) {
    int4 v = *(const int4*)&deg[base];
    s = v.x + v.y + v.z + v.w;
  }
  red[t] = s;
  __syncthreads();
  #pragma unroll
  for (int off = 128; off > 0; off >>= 1) {
    if (t < off) red[t] += red[t + off];
    __syncthreads();
  }
  if (t == 0) bsum[blockIdx.x] = red[0];
}

// phase 2 (merged): each block scans the 98 partials in LDS, then local scan
__global__ __launch_bounds__(256) void scan3(
    const int* __restrict__ deg, const int* __restrict__ bsum,
    int* __restrict__ rowptr, int* __restrict__ cursor)
{
  __shared__ int sc[256];
  __shared__ int bs[128];
  const int t = threadIdx.x;
  if (t < 128) bs[t] = (t < SCAN_BLOCKS) ? bsum[t] : 0;
  __syncthreads();
  #pragma unroll
  for (int off = 1; off < 128; off <<= 1) {
    int v = (t >= off && t < 128) ? bs[t - off] : 0;
    __syncthreads();
    if (t < 128) bs[t] += v;
    __syncthreads();
  }
  const int myoff = (blockIdx.x == 0) ? 0 : bs[blockIdx.x - 1];

  int base = (blockIdx.x << 10) + (t << 2);
  int4 v = {0, 0, 0, 0};
  if (base + 4 <= NBINS) v = *(const int4*)&deg[base];
  int s = v.x + v.y + v.z + v.w;
  sc[t] = s;
  __syncthreads();
  #pragma unroll
  for (int off = 1; off < 256; off <<= 1) {
    int u = (t >= off) ? sc[t - off] : 0;
    __syncthreads();
    sc[t] += u;
    __syncthreads();
  }
  if (base + 4 <= NBINS) {
    int p = myoff + ((t == 0) ? 0 : sc[t - 1]);
    int4 r;
    r.x = p; r.y = p + v.x; r.z = r.y + v.y; r.w = r.z + v.z;
    *(int4*)&rowptr[base] = r;
    *(int4*)&cursor[base] = r;
  }
  if (blockIdx.x == SCAN_BLOCKS - 1 && t == 255) rowptr[NBINS] = bs[127];
}

__global__ __launch_bounds__(256) void csr_fill(
    const int* __restrict__ esrc, const int* __restrict__ edst,
    int* __restrict__ cursor, int* __restrict__ csr_src)
{
  int e = blockIdx.x * 256 + threadIdx.x;
  if (e >= E_TOT) return;
  int src, dst;
  if (e < E_ORIG) { src = esrc[e]; dst = edst[e]; }
  else            { src = dst = e - E_ORIG; }
  int pos = atomicAdd(&cursor[dst * NCHUNK + (src >> 12)], 1);
  csr_src[pos] = src;
}

// ============ bf16 MFMA GEMM: C[M,N] = A[M,K] @ Bt[N,K]^T ============
__global__ __launch_bounds__(256) void mfma_gemm_bf16(
    const ushort* __restrict__ A, const ushort* __restrict__ Bt,
    ushort* __restrict__ C, int M, int K, int N)
{
  __shared__ char smem[36864];
  ushort* As = (ushort*)smem;           // [128][64]
  ushort* Bs = As + 8192;               // [128][64]

  const int mtiles = (M + 127) >> 7;
  const int bid = blockIdx.x;
  const int xcd = bid & 7;
  const int i = bid >> 3;
  const int n0 = (i / 20) << 7;
  const int m = xcd + ((i % 20) << 3);
  if (m >= mtiles) return;
  const int m0 = m << 7;

  const int tid = threadIdx.x;
  const int lane = tid & 63;
  const int w = tid >> 6;
  const int wm = (w >> 1) << 6;
  const int wn = (w & 1) << 6;
  const int quad = lane >> 4;
  const int l15 = lane & 15;

  f32x4 acc[4][4] = {};

  for (int k0 = 0; k0 < K; k0 += 64) {
    #pragma unroll
    for (int r = 0; r < 4; r++) {
      int c = (r << 8) + tid;
      int row = c >> 3;
      int col = (c & 7) << 3;
      int ga = m0 + row; if (ga >= M) ga = M - 1;
      gl_lds16(A  + (size_t)ga * K + k0 + col, (char*)As + c * 16);
      gl_lds16(Bt + (size_t)(n0 + row) * K + k0 + col, (char*)Bs + c * 16);
    }
    __syncthreads();
    #pragma unroll
    for (int ks = 0; ks < 2; ks++) {
      bf16x8 af[4], bfr[4];
      #pragma unroll
      for (int ii = 0; ii < 4; ii++)
        af[ii]  = *(const bf16x8*)&As[(wm + (ii << 4) + l15) * 64 + (ks << 5) + (quad << 3)];
      #pragma unroll
      for (int j = 0; j < 4; j++)
        bfr[j] = *(const bf16x8*)&Bs[(wn + (j << 4) + l15) * 64 + (ks << 5) + (quad << 3)];
      #pragma unroll
      for (int ii = 0; ii < 4; ii++)
        #pragma unroll
        for (int j = 0; j < 4; j++)
          acc[ii][j] = __builtin_amdgcn_mfma_f32_16x16x32_bf16(
              af[ii], bfr[j], acc[ii][j], 0, 0, 0);
    }
    __syncthreads();
  }

  ushort* Cs = (ushort*)smem + w * 4608;
  #pragma unroll
  for (int ii = 0; ii < 4; ii++)
    #pragma unroll
    for (int j = 0; j < 4; j++)
      #pragma unroll
      for (int r = 0; r < 4; r++)
        Cs[((ii << 4) + (quad << 2) + r) * 72 + (j << 4) + l15] = f2bf(acc[ii][j][r]);
  #pragma unroll
  for (int it = 0; it < 8; it++) {
    int row = (it << 3) + (lane >> 3);
    int cc = lane & 7;
    bf16x8 v = *(const bf16x8*)&Cs[row * 72 + (cc << 3)];
    int grow = m0 + wm + row;
    if (grow < M)
      *(bf16x8*)&C[(size_t)grow * N + n0 + wn + (cc << 3)] = v;
  }
}

// ============ GATv2 edge phase, H=4, bf16, 8 edges in flight ============
__device__ __forceinline__ void h4_term(
    float4 xlv, const float4& xrv, const float4& attv, float& v)
{
  float4 a;
  a.x = xlv.x + xrv.x; a.y = xlv.y + xrv.y;
  a.z = xlv.z + xrv.z; a.w = xlv.w + xrv.w;
  a.x = fmaxf(a.x, 0.2f * a.x); a.y = fmaxf(a.y, 0.2f * a.y);
  a.z = fmaxf(a.z, 0.2f * a.z); a.w = fmaxf(a.w, 0.2f * a.w);
  v = a.x * attv.x + a.y * attv.y + a.z * attv.z + a.w * attv.w;
}

// per-head 16-lane butterfly + exp + accumulate for one edge
__device__ __forceinline__ void h4_edge(
    const float4& xv, const float4& xrv, const float4& attv,
    float4& acc, float& lsum)
{
  float v;
  h4_term(xv, xrv, attv, v);
  v += __shfl_xor(v, 1);
  v += __shfl_xor(v, 2);
  v += __shfl_xor(v, 4);
  v += __shfl_xor(v, 8);
  float w = __expf(v);            // no-max softmax: logits O(1), safe
  lsum += w;
  acc.x += w * xv.x; acc.y += w * xv.y;
  acc.z += w * xv.z; acc.w += w * xv.w;
}

__global__ __launch_bounds__(256) void gat_gather_h4(
    const ushort* __restrict__ Cin, const float* __restrict__ att,
    const float* __restrict__ bias, const int* __restrict__ rowptr,
    const int* __restrict__ csr_src, ushort* __restrict__ hout)
{
  const int n = blockIdx.x * 4 + (threadIdx.x >> 6);
  const int lane = threadIdx.x & 63;
  const int c4 = lane << 2;
  const float4 xrv  = ld_bf16x4(Cin + (size_t)n * 512 + 256 + c4);
  const float4 attv = *(const float4*)&att[c4];
  const int beg = rowptr[n * NCHUNK], end = rowptr[n * NCHUNK + NCHUNK];
  float4 acc = make_float4(0.f, 0.f, 0.f, 0.f);
  float lsum = 0.f;
  int p = beg;
  for (; p + 7 < end; p += 8) {        // 8 loads issued before any consume
    int s0 = csr_src[p],     s1 = csr_src[p + 1];
    int s2 = csr_src[p + 2], s3 = csr_src[p + 3];
    int s4 = csr_src[p + 4], s5 = csr_src[p + 5];
    int s6 = csr_src[p + 6], s7 = csr_src[p + 7];
    float4 x0 = ld_bf16x4(Cin + (size_t)s0 * 512 + c4);
    float4 x1 = ld_bf16x4(Cin + (size_t)s1 * 512 + c4);
    float4 x2 = ld_bf16x4(Cin + (size_t)s2 * 512 + c4);
    float4 x3 = ld_bf16x4(Cin + (size_t)s3 * 512 + c4);
    float4 x4 = ld_bf16x4(Cin + (size_t)s4 * 512 + c4);
    float4 x5 = ld_bf16x4(Cin + (size_t)s5 * 512 + c4);
    float4 x6 = ld_bf16x4(Cin + (size_t)s6 * 512 + c4);
    float4 x7 = ld_bf16x4(Cin + (size_t)s7 * 512 + c4);
    h4_edge(x0, xrv, attv, acc, lsum);
    h4_edge(x1, xrv, attv, acc, lsum);
    h4_edge(x2, xrv, attv, acc, lsum);
    h4_edge(x3, xrv, attv, acc, lsum);
    h4_edge(x4, xrv, attv, acc, lsum);
    h4_edge(x5, xrv, attv, acc, lsum);
    h4_edge(x6, xrv, attv, acc, lsum);
    h4_edge(x7, xrv, attv, acc, lsum);
  }
  for (; p + 3 < end; p += 4) {
    int s0 = csr_src[p],     s1 = csr_src[p + 1];
    int s2 = csr_src[p + 2], s3 = csr_src[p + 3];
    float4 x0 = ld_bf16x4(Cin + (size_t)s0 * 512 + c4);
    float4 x1 = ld_bf16x4(Cin + (size_t)s1 * 512 + c4);
    float4 x2 = ld_bf16x4(Cin + (size_t)s2 * 512 + c4);
    float4 x3 = ld_bf16x4(Cin + (size_t)s3 * 512 + c4);
    h4_edge(x0, xrv, attv, acc, lsum);
    h4_edge(x1, xrv, attv, acc, lsum);
    h4_edge(x2, xrv, attv, acc, lsum);
    h4_edge(x3, xrv, attv, acc, lsum);
  }
  for (; p < end; p++) {
    int s0 = csr_src[p];
    float4 x0 = ld_bf16x4(Cin + (size_t)s0 * 512 + c4);
    h4_edge(x0, xrv, attv, acc, lsum);
  }
  const float4 bv = *(const float4*)&bias[c4];
  float inv = 1.f / lsum;
  ushort4 o;
  o.x = f2bf(acc.x * inv + bv.x); o.y = f2bf(acc.y * inv + bv.y);
  o.z = f2bf(acc.z * inv + bv.z); o.w = f2bf(acc.w * inv + bv.w);
  *(ushort4*)&hout[(size_t)n * 256 + c4] = o;
}

// ============ layer 2 (H=1): 16-lane groups, 2 edges in flight ============
__global__ __launch_bounds__(256) void gat_gather_h1(
    const ushort* __restrict__ Cin, const float* __restrict__ att,
    const float* __restrict__ bias, const int* __restrict__ rowptr,
    const int* __restrict__ csr_src, float* __restrict__ h3)
{
  const int n = blockIdx.x * 4 + (threadIdx.x >> 6);
  const int lane = threadIdx.x & 63;
  const int g = lane >> 4, c4 = (lane & 15) << 2;
  const float4 xrv  = ld_bf16x4(Cin + (size_t)n * 128 + 64 + c4);
  const float4 attv = *(const float4*)&att[c4];
  const int beg = rowptr[n * NCHUNK], end = rowptr[n * NCHUNK + NCHUNK];
  float4 acc = make_float4(0.f, 0.f, 0.f, 0.f);
  float lsum = 0.f;
  int p = beg + g;
  for (; p + 4 < end; p += 8) {        // 2 strided edges in flight
    int s0 = csr_src[p], s1 = csr_src[p + 4];
    float4 x0 = ld_bf16x4(Cin + (size_t)s0 * 128 + c4);
    float4 x1 = ld_bf16x4(Cin + (size_t)s1 * 128 + c4);
    h4_edge(x0, xrv, attv, acc, lsum);
    h4_edge(x1, xrv, attv, acc, lsum);
  }
  if (p < end) {
    int s0 = csr_src[p];
    float4 x0 = ld_bf16x4(Cin + (size_t)s0 * 128 + c4);
    h4_edge(x0, xrv, attv, acc, lsum);
  }
  #pragma unroll
  for (int off = 16; off <= 32; off <<= 1) {
    lsum  += __shfl_xor(lsum, off);
    acc.x += __shfl_xor(acc.x, off); acc.y += __shfl_xor(acc.y, off);
    acc.z += __shfl_xor(acc.z, off); acc.w += __shfl_xor(acc.w, off);
  }
  if (g == 0) {
    const float4 bv = *(const float4*)&bias[c4];
    float inv = 1.f / lsum;
    float4 o;
    o.x = acc.x * inv + bv.x; o.y = acc.y * inv + bv.y;
    o.z = acc.z * inv + bv.z; o.w = acc.w * inv + bv.w;
    *(float4*)&h3[(size_t)n * 64 + c4] = o;
  }
}

// ============ fused segmented pool (batch sorted) + BN + fc ============
__global__ __launch_bounds__(256) void pool_bn_fc(
    const float* __restrict__ h3, const int* __restrict__ batch,
    const float* __restrict__ gamma, const float* __restrict__ beta,
    const float* __restrict__ mean, const float* __restrict__ var,
    const float* __restrict__ fcw, const float* __restrict__ fcb,
    float* __restrict__ out)
{
  __shared__ float red[256];
  __shared__ float s[64];
  const int g = blockIdx.x;
  const int t = threadIdx.x;
  const int c = t & 63, r = t >> 6;
  int lo = 0, hi = N_NODES;
  while (lo < hi) { int mid = (lo + hi) >> 1; if (batch[mid] < g) lo = mid + 1; else hi = mid; }
  int s0 = lo;
  hi = N_NODES;
  while (lo < hi) { int mid = (lo + hi) >> 1; if (batch[mid] < g + 1) lo = mid + 1; else hi = mid; }
  int e0 = lo;
  float a = 0.f;
  for (int n = s0 + r; n < e0; n += 4) a += h3[(size_t)n * 64 + c];
  red[t] = a;
  __syncthreads();
  if (r == 0) {
    float p = red[c] + red[c + 64] + red[c + 128] + red[c + 192];
    s[c] = (p - mean[c]) * rsqrtf(var[c] + 1e-5f) * gamma[c] + beta[c];
  }
  __syncthreads();
  if (t < 32) {
    float acc = fcb[t];
    #pragma unroll
    for (int k = 0; k < 64; k++) acc += s[k] * fcw[k * 32 + t];
    out[g * 32 + t] = acc;
  }
}

extern "C" void kernel_launch(void* const* d_in, const int* in_sizes, int n_in,
                              void* d_out, int out_size, void* d_ws, size_t ws_size,
                              hipStream_t stream) {
  const float* x    = (const float*)d_in[0];
  const int*   ei   = (const int*)d_in[1];
  const int*   batch= (const int*)d_in[2];
  const float* Wl0  = (const float*)d_in[3];
  const float* Wr0  = (const float*)d_in[4];
  const float* att0 = (const float*)d_in[5];
  const float* b0   = (const float*)d_in[6];
  const float* Wl1  = (const float*)d_in[7];
  const float* Wr1  = (const float*)d_in[8];
  const float* att1 = (const float*)d_in[9];
  const float* b1   = (const float*)d_in[10];
  const float* Wl2  = (const float*)d_in[11];
  const float* Wr2  = (const float*)d_in[12];
  const float* att2 = (const float*)d_in[13];
  const float* b2   = (const float*)d_in[14];
  const float* bng  = (const float*)d_in[15];
  const float* bnb  = (const float*)d_in[16];
  const float* bnm  = (const float*)d_in[17];
  const float* bnv  = (const float*)d_in[18];
  const float* fcw  = (const float*)d_in[19];
  const float* fcb  = (const float*)d_in[20];
  float* out = (float*)d_out;

  const int* esrc = ei;
  const int* edst = ei + E_ORIG;

  // ---- workspace layout ----
  char* w = (char*)d_ws;
  ushort* x16  = (ushort*)w;                 w += (size_t)N_NODES * 128 * 2;
  ushort* Cbig = (ushort*)w;                 w += (size_t)N_NODES * 512 * 2;
  ushort* h16  = (ushort*)w;                 w += (size_t)N_NODES * 256 * 2;
  ushort* C2   = (ushort*)w;                 w += (size_t)N_NODES * 128 * 2;
  float*  h3   = (float*)w;                  w += (size_t)N_NODES * 64 * 4;
  ushort* Bt0  = (ushort*)w;                 w += (size_t)512 * 128 * 2;
  ushort* Bt1  = (ushort*)w;                 w += (size_t)512 * 256 * 2;
  ushort* Bt2  = (ushort*)w;                 w += (size_t)128 * 256 * 2;
  int* deg     = (int*)w;                    w += NBINS * 4;
  int* rowptr  = (int*)w;                    w += (NBINS + 1) * 4;
  int* cursor  = (int*)w;                    w += NBINS * 4;
  int* bsum    = (int*)w;                    w += 128 * 4;
  int* csr_src = (int*)w;

  dim3 blk(256);
  const int eblk = (E_TOT + 255) / 256;

  // ---- prep: cast + pack all weights + zero bins (one launch) ----
  prep<<<dim3(3495), blk, 0, stream>>>(
      x, Wl0, Wr0, Wl1, Wr1, Wl2, Wr2, x16, Bt0, Bt1, Bt2, deg);

  // ---- CSR build, (dst, src-chunk) binned; 2-kernel parallel scan ----
  deg_count<<<dim3(eblk), blk, 0, stream>>>(esrc, edst, deg);
  scan1<<<dim3(SCAN_BLOCKS), blk, 0, stream>>>(deg, bsum);
  scan3<<<dim3(SCAN_BLOCKS), blk, 0, stream>>>(deg, bsum, rowptr, cursor);
  csr_fill<<<dim3(eblk), blk, 0, stream>>>(esrc, edst, cursor, csr_src);

  // ---- layer 0 ----
  mfma_gemm_bf16<<<dim3(160 * 4), blk, 0, stream>>>(x16, Bt0, Cbig, N_NODES, 128, 512);
  gat_gather_h4<<<dim3(N_NODES / 4), blk, 0, stream>>>(
      Cbig, att0, b0, rowptr, csr_src, h16);

  // ---- layer 1 ----
  mfma_gemm_bf16<<<dim3(160 * 4), blk, 0, stream>>>(h16, Bt1, Cbig, N_NODES, 256, 512);
  gat_gather_h4<<<dim3(N_NODES / 4), blk, 0, stream>>>(
      Cbig, att1, b1, rowptr, csr_src, h16);

  // ---- layer 2 ----
  mfma_gemm_bf16<<<dim3(160 * 1), blk, 0, stream>>>(h16, Bt2, C2, N_NODES, 256, 128);
  gat_gather_h1<<<dim3(N_NODES / 4), blk, 0, stream>>>(
      C2, att2, b2, rowptr, csr_src, h3);

  // ---- pool + BN + fc ----
  pool_bn_fc<<<dim3(NUM_GRAPHS), blk, 0, stream>>>(
      h3, batch, bng, bnb, bnm, bnv, fcw, fcb, out);
}